// Round 8
// baseline (677.278 us; speedup 1.0000x reference)
//
#include <hip/hip_runtime.h>
#include <math.h>

#define N_PIX 3136
#define C_DIM 192
#define HID_DIM 384
#define KNN 9
#define EPS_BN 1e-5f

typedef __attribute__((ext_vector_type(4))) float f32x4;
typedef __attribute__((ext_vector_type(16))) float f32x16;
typedef __attribute__((ext_vector_type(8))) short s16x8;
typedef unsigned short u16;

// ---------------- workspace layout (float units) ----------------
static const size_t OFF_H   = 0;            // h fp32: 12544*192
static const size_t OFF_SQ  = 2408448;      // sq: 12544
static const size_t OFF_H2  = 2420992;      // h2 u16 [hi192|lo192]
static const size_t OFF_G2  = 0;            // g2 u16 overlay
static const size_t OFF_PBF = 4829440;      // P bf16
static const size_t OFF_QBF = 7237888;      // Q bf16
static const size_t OFF_WC2 = 9646336;      // wc2 u16 768*384
static const size_t OFF_W5  = 9793792;      // w5 u16 192*768
static const size_t OFF_CST = 9867520;      // 1536 f
static const size_t OFF_IDX = 9869056;      // 112,896 int
static const size_t OFF_PL  = 9981952;      // 12544*7*9 u64

__device__ inline u16 f2bf_rn(float x) {
    unsigned u = __float_as_uint(x);
    unsigned r = u + 0x7fffu + ((u >> 16) & 1u);
    return (u16)(r >> 16);
}
__device__ inline float bf2f(u16 v) { return __uint_as_float((unsigned)v << 16); }
__device__ inline void split2(float x, u16& hi, u16& lo) {
    hi = f2bf_rn(x);
    lo = f2bf_rn(x - bf2f(hi));
}

// ---------------- prep: wc2/w5 bf16 splits + BN scale/shift ----------------
__global__ void k_prep(const float* __restrict__ gcn_w, const float* __restrict__ fc2_w,
                       const float* __restrict__ bn1_g, const float* __restrict__ bn1_b,
                       const float* __restrict__ bn1_m, const float* __restrict__ bn1_v,
                       const float* __restrict__ bng_g, const float* __restrict__ bng_b,
                       const float* __restrict__ bng_m, const float* __restrict__ bng_v,
                       const float* __restrict__ bn2_g, const float* __restrict__ bn2_b,
                       const float* __restrict__ bn2_m, const float* __restrict__ bn2_v,
                       u16* __restrict__ wc2, u16* __restrict__ w5, float* __restrict__ cst)
{
    int t = blockIdx.x * 256 + threadIdx.x;
    if (t < 768 * 192) {
        int o = t / 192, c = t % 192;
        float v = (o < 384) ? gcn_w[o * 384 + c] - gcn_w[o * 384 + 192 + c]
                            : gcn_w[(o - 384) * 384 + 192 + c];
        u16 hi, lo; split2(v, hi, lo);
        wc2[(size_t)o * 384 + c] = hi;
        wc2[(size_t)o * 384 + 192 + c] = lo;
    } else if (t < 768 * 192 + 192 * 384) {
        int u = t - 768 * 192;
        int c = u / 384, k = u % 384;
        u16 hi, lo; split2(fc2_w[(size_t)c * 384 + k], hi, lo);
        w5[(size_t)c * 768 + k] = hi;
        w5[(size_t)c * 768 + 384 + k] = lo;
    } else if (t < 768 * 192 + 192 * 384 + 768) {
        int u = t - 768 * 192 - 192 * 384;
        if (u < 192) {
            float s = bn1_g[u] / sqrtf(bn1_v[u] + EPS_BN);
            cst[u] = s; cst[192 + u] = bn1_b[u] - bn1_m[u] * s;
        } else if (u < 576) {
            int ch = u - 192;
            float s = bng_g[ch] / sqrtf(bng_v[ch] + EPS_BN);
            cst[384 + ch] = s; cst[768 + ch] = bng_b[ch] - bng_m[ch] * s;
        } else {
            int ch = u - 576;
            float s = bn2_g[ch] / sqrtf(bn2_v[ch] + EPS_BN);
            cst[1152 + ch] = s; cst[1344 + ch] = bn2_b[ch] - bn2_m[ch] * s;
        }
    }
}

// ---------------- K1: h = bn1(xf @ fc1_w^T + fc1_b)  (fp32 VALU GEMM) ----------------
__global__ __launch_bounds__(256) void k1_fc1_bn1(
    const float* __restrict__ x, const float* __restrict__ w,
    const float* __restrict__ bias, const float* __restrict__ cst,
    float* __restrict__ h)
{
    __shared__ float As[32][64];
    __shared__ float Bs[32][64];
    int bx = blockIdx.x;
    int o0 = blockIdx.y * 64;
    int b  = bx / 49;
    int n0 = (bx % 49) * 64;
    const float* xb = x + (size_t)b * C_DIM * N_PIX;
    int t = threadIdx.x;
    int tx = t & 15, ty = t >> 4;
    float acc[4][4] = {};
    for (int kc = 0; kc < 6; ++kc) {
        #pragma unroll
        for (int p = 0; p < 2; ++p) {
            int idx = t + p * 256;
            int kk = idx >> 4, j4 = idx & 15;
            float4 v = *reinterpret_cast<const float4*>(xb + (size_t)(kc * 32 + kk) * N_PIX + n0 + j4 * 4);
            *reinterpret_cast<float4*>(&As[kk][j4 * 4]) = v;
        }
        #pragma unroll
        for (int p = 0; p < 2; ++p) {
            int idx = t + p * 256;
            int oo = idx >> 3, c4 = idx & 7;
            float4 v = *reinterpret_cast<const float4*>(w + (size_t)(o0 + oo) * C_DIM + kc * 32 + c4 * 4);
            Bs[c4 * 4 + 0][oo] = v.x; Bs[c4 * 4 + 1][oo] = v.y;
            Bs[c4 * 4 + 2][oo] = v.z; Bs[c4 * 4 + 3][oo] = v.w;
        }
        __syncthreads();
        #pragma unroll
        for (int kk = 0; kk < 32; ++kk) {
            float4 av = *reinterpret_cast<const float4*>(&As[kk][ty * 4]);
            float4 bv = *reinterpret_cast<const float4*>(&Bs[kk][tx * 4]);
            float a[4] = {av.x, av.y, av.z, av.w};
            float bb[4] = {bv.x, bv.y, bv.z, bv.w};
            #pragma unroll
            for (int i = 0; i < 4; ++i)
                #pragma unroll
                for (int j = 0; j < 4; ++j) acc[i][j] += a[i] * bb[j];
        }
        __syncthreads();
    }
    #pragma unroll
    for (int i = 0; i < 4; ++i) {
        int n = n0 + ty * 4 + i;
        size_t r = (size_t)b * N_PIX + n;
        float vals[4];
        #pragma unroll
        for (int j = 0; j < 4; ++j) {
            int o = o0 + tx * 4 + j;
            vals[j] = (acc[i][j] + bias[o]) * cst[o] + cst[192 + o];
        }
        *reinterpret_cast<float4*>(h + r * C_DIM + o0 + tx * 4) =
            make_float4(vals[0], vals[1], vals[2], vals[3]);
    }
}

// ---------------- K1b: sq[r] = sum_c h[r][c]^2 ----------------
__global__ __launch_bounds__(256) void k_sq(const float* __restrict__ h, float* __restrict__ sq)
{
    int r = blockIdx.x * 256 + threadIdx.x;
    const float* hr = h + (size_t)r * C_DIM;
    float s = 0.f;
    #pragma unroll
    for (int c = 0; c < C_DIM; c += 4) {
        float4 v = *reinterpret_cast<const float4*>(hr + c);
        s += v.x * v.x + v.y * v.y + v.z * v.z + v.w * v.w;
    }
    sq[r] = s;
}

// ---------------- K1c: split h into bf16 hi|lo ----------------
__global__ __launch_bounds__(256) void k_split(const float* __restrict__ h, u16* __restrict__ h2)
{
    int t = blockIdx.x * 256 + threadIdx.x;
    int base = t * 4;
    int r = base / C_DIM, c = base % C_DIM;
    float4 v = *reinterpret_cast<const float4*>(h + base);
    float f[4] = {v.x, v.y, v.z, v.w};
    u16* dst = h2 + (size_t)r * 384 + c;
    #pragma unroll
    for (int j = 0; j < 4; ++j) {
        u16 hi, lo; split2(f[j], hi, lo);
        dst[j] = hi; dst[192 + j] = lo;
    }
}

// ---------------- K3: 32x32x16 MFMA dist + decoupled wave-private select ----------------
// grid 1372 blocks (4b*49strip*7mc), 128 thr (2 waves).
// Wave w owns n-rows n0+32w..+31: A-frags (full K, hi+lo = 96 VGPR) pinned in regs.
// B-tile 32m x 384u16 in LDS, b128-chunk XOR swizzle (chunk ^= row&7).
// Epilogue writes sqm-2*dot into wave-private swizzled key tile (no barrier);
// select: lane owns (row=lane>>1, half=lane&1), scans 16 keys/step into sorted-9.
__global__ void __attribute__((amdgpu_waves_per_eu(2, 3))) k3_knn(
    const u16* __restrict__ h2, const float* __restrict__ sq,
    unsigned long long* __restrict__ pl)
{
    __shared__ u16 Bs[32 * 384];        // 24576 B
    __shared__ float keyt[2][32 * 32];  // 8192 B
    int bx = blockIdx.x;
    int b = bx / 343, rem = bx % 343;
    int strip = rem / 7, mc = rem % 7;
    int n0 = strip * 64;
    const u16* hb = h2 + (size_t)b * N_PIX * 384;
    const float* sqb = sq + (size_t)b * N_PIX;
    int t = threadIdx.x;
    int lane = t & 63, w = t >> 6;
    int ml = lane & 31, kg = lane >> 5;

    // A fragments: row = n0 + w*32 + ml, k = kc*16 + kg*8 (+192 for lo)
    s16x8 a_hi[12], a_lo[12];
    {
        const u16* ar = hb + (size_t)(n0 + w * 32 + ml) * 384 + kg * 8;
        #pragma unroll
        for (int kc = 0; kc < 12; ++kc) {
            a_hi[kc] = *reinterpret_cast<const s16x8*>(ar + kc * 16);
            a_lo[kc] = *reinterpret_cast<const s16x8*>(ar + 192 + kc * 16);
        }
    }
    // opaque defs: the loads cannot be rematerialized past these
    #pragma unroll
    for (int kc = 0; kc < 12; ++kc)
        asm volatile("" : "+v"(a_hi[kc]), "+v"(a_lo[kc]));

    int srow = lane >> 1, seg = lane & 1;
    float sqn_r = sqb[n0 + w * 32 + srow];
    unsigned long long cand[KNN];
    #pragma unroll
    for (int q = 0; q < KNN; ++q) cand[q] = ~0ull;

    float* kt = keyt[w];
    int swz = ml & 7;
    for (int step = 0; step < 14; ++step) {
        int m0 = mc * 448 + step * 32;
        __syncthreads();
        #pragma unroll
        for (int p = 0; p < 12; ++p) {         // stage 32 rows x 768B, swizzled
            int cl = p * 128 + t;
            int row = cl / 48, ch = cl % 48;
            s16x8 v = *reinterpret_cast<const s16x8*>(hb + (size_t)(m0 + row) * 384 + ch * 8);
            *reinterpret_cast<s16x8*>(&Bs[row * 384 + ((ch ^ (row & 7)) * 8)]) = v;
        }
        __syncthreads();

        f32x16 acc;
        #pragma unroll
        for (int i = 0; i < 16; ++i) acc[i] = 0.0f;
        const s16x8* bsrow = reinterpret_cast<const s16x8*>(&Bs[ml * 384]);
        #pragma unroll
        for (int kc = 0; kc < 12; ++kc) {
            s16x8 bh = bsrow[(kc * 2 + kg) ^ swz];
            s16x8 bl = bsrow[(24 + kc * 2 + kg) ^ swz];
            acc = __builtin_amdgcn_mfma_f32_32x32x16_bf16(a_hi[kc], bh, acc, 0, 0, 0);
            acc = __builtin_amdgcn_mfma_f32_32x32x16_bf16(a_hi[kc], bl, acc, 0, 0, 0);
            acc = __builtin_amdgcn_mfma_f32_32x32x16_bf16(a_lo[kc], bh, acc, 0, 0, 0);
        }
        // epilogue: kt[n_loc][swz(m_loc)] = sqm - 2*dot  (C: col=lane&31, row=(r&3)+8*(r>>2)+4*kg)
        float sqm = sqb[m0 + ml];
        #pragma unroll
        for (int r = 0; r < 16; ++r) {
            int nl = (r & 3) + 8 * (r >> 2) + 4 * kg;
            int chp = (ml >> 2) ^ (nl & 7);
            kt[nl * 32 + chp * 4 + (ml & 3)] = fmaf(-2.0f, acc[r], sqm);
        }
        // wave-private select (no barrier)
        #pragma unroll
        for (int jc = 0; jc < 4; ++jc) {
            int ch = seg * 4 + jc;
            f32x4 kv = *reinterpret_cast<const f32x4*>(&kt[srow * 32 + ((ch ^ (srow & 7)) * 4)]);
            #pragma unroll
            for (int e = 0; e < 4; ++e) {
                float dist = kv[e] + sqn_r;
                int m = m0 + seg * 16 + jc * 4 + e;
                unsigned u = __float_as_uint(dist);
                u = (u & 0x80000000u) ? ~u : (u | 0x80000000u);
                unsigned long long key = ((unsigned long long)u << 32) | (unsigned)m;
                if (key < cand[KNN - 1]) {
                    cand[KNN - 1] = key;
                    #pragma unroll
                    for (int q = KNN - 1; q > 0; --q) {
                        unsigned long long lo2 = cand[q - 1], hi2 = cand[q];
                        if (hi2 < lo2) { cand[q - 1] = hi2; cand[q] = lo2; }
                    }
                }
            }
        }
    }
    // merge the 2 half-lists per row (lanes 2r, 2r+1); write sorted 9
    {
        int n = n0 + w * 32 + srow;
        size_t rowg = (size_t)b * N_PIX + n;
        for (int r = 0; r < KNN; ++r) {
            unsigned long long my = cand[0];
            unsigned long long gm = my;
            unsigned long long o = __shfl_xor(gm, 1);
            if (o < gm) gm = o;
            if (gm == my) {
                #pragma unroll
                for (int q = 0; q < KNN - 1; ++q) cand[q] = cand[q + 1];
                cand[KNN - 1] = ~0ull;
            }
            if (seg == 0)
                pl[(rowg * 7 + mc) * KNN + r] = gm;
        }
    }
}

// ---------------- K3b: merge 7 sorted partial lists -> final idx ----------------
__global__ __launch_bounds__(256) void k3b_merge(
    const unsigned long long* __restrict__ pl, int* __restrict__ idxout)
{
    int r = blockIdx.x * 256 + threadIdx.x;
    const unsigned long long* base = pl + (size_t)r * 63;
    unsigned long long list[KNN];
    #pragma unroll
    for (int q = 0; q < KNN; ++q) list[q] = ~0ull;
    for (int c = 0; c < 63; ++c) {
        unsigned long long k = base[c];
        if (k < list[KNN - 1]) {
            list[KNN - 1] = k;
            #pragma unroll
            for (int q = KNN - 1; q > 0; --q) {
                unsigned long long lo = list[q - 1], hi = list[q];
                if (hi < lo) { list[q - 1] = hi; list[q] = lo; }
            }
        }
    }
    #pragma unroll
    for (int q = 0; q < KNN; ++q)
        idxout[(size_t)r * KNN + q] = (int)(list[q] & 0xffffffffu);
}

// ---------------- K2: P,Q = h @ Wc^T (+bias) -> bf16, MFMA, no LDS ----------------
__global__ __launch_bounds__(256, 2) void k2_pq(
    const u16* __restrict__ h2, const u16* __restrict__ wc2,
    const float* __restrict__ gcnb, u16* __restrict__ Pbf, u16* __restrict__ Qbf)
{
    int r0 = blockIdx.x * 64;
    int o0 = blockIdx.y * 32;
    int t = threadIdx.x, lane = t & 63, w = t >> 6;
    int col16 = lane & 15, g = lane >> 4;

    s16x8 a_hi[6], a_lo[6];
    {
        const u16* ar = h2 + (size_t)(r0 + w * 16 + col16) * 384;
        #pragma unroll
        for (int ko = 0; ko < 6; ++ko) {
            a_hi[ko] = *reinterpret_cast<const s16x8*>(ar + ko * 32 + g * 8);
            a_lo[ko] = *reinterpret_cast<const s16x8*>(ar + 192 + ko * 32 + g * 8);
        }
    }
    const u16* br = wc2 + (size_t)(o0 + col16) * 384 + g * 8;
    f32x4 acc0 = {0.f, 0.f, 0.f, 0.f};
    f32x4 acc1 = {0.f, 0.f, 0.f, 0.f};
    #pragma unroll
    for (int ko = 0; ko < 6; ++ko) {
        s16x8 b0h = *reinterpret_cast<const s16x8*>(br + ko * 32);
        s16x8 b0l = *reinterpret_cast<const s16x8*>(br + 192 + ko * 32);
        s16x8 b1h = *reinterpret_cast<const s16x8*>(br + 16 * 384 + ko * 32);
        s16x8 b1l = *reinterpret_cast<const s16x8*>(br + 16 * 384 + 192 + ko * 32);
        acc0 = __builtin_amdgcn_mfma_f32_16x16x32_bf16(a_hi[ko], b0h, acc0, 0, 0, 0);
        acc0 = __builtin_amdgcn_mfma_f32_16x16x32_bf16(a_hi[ko], b0l, acc0, 0, 0, 0);
        acc0 = __builtin_amdgcn_mfma_f32_16x16x32_bf16(a_lo[ko], b0h, acc0, 0, 0, 0);
        acc1 = __builtin_amdgcn_mfma_f32_16x16x32_bf16(a_hi[ko], b1h, acc1, 0, 0, 0);
        acc1 = __builtin_amdgcn_mfma_f32_16x16x32_bf16(a_hi[ko], b1l, acc1, 0, 0, 0);
        acc1 = __builtin_amdgcn_mfma_f32_16x16x32_bf16(a_lo[ko], b1h, acc1, 0, 0, 0);
    }
    bool isP = (o0 < HID_DIM);
    #pragma unroll
    for (int oq = 0; oq < 2; ++oq) {
        int o = o0 + oq * 16 + col16;
        float bias = isP ? gcnb[o] : 0.0f;
        #pragma unroll
        for (int i = 0; i < 4; ++i) {
            size_t r = (size_t)(r0 + w * 16 + g * 4 + i);
            float v = (oq ? acc1[i] : acc0[i]) + bias;
            u16 bv = f2bf_rn(v);
            if (isP) Pbf[r * 384 + o] = bv;
            else     Qbf[r * 384 + (o - HID_DIM)] = bv;
        }
    }
}

// ---------------- K4: g2 = split(gelu(bn_g(P + max_k Q[idx[k]]))) ----------------
__global__ __launch_bounds__(384) void k4_agg(
    const u16* __restrict__ Pbf, const u16* __restrict__ Qbf,
    const int* __restrict__ idx, const float* __restrict__ cst,
    u16* __restrict__ g2)
{
    int blk = blockIdx.x;
    int b = blk / N_PIX;
    size_t row = (size_t)blk;
    const int* id = idx + row * KNN;
    int o = threadIdx.x;
    const u16* Qb = Qbf + (size_t)b * N_PIX * 384;
    float v = -INFINITY;
    #pragma unroll
    for (int k = 0; k < KNN; ++k)
        v = fmaxf(v, bf2f(Qb[(size_t)id[k] * 384 + o]));
    float p = bf2f(Pbf[row * 384 + o]);
    float y = (p + v) * cst[384 + o] + cst[768 + o];
    float ge = 0.5f * y * (1.0f + erff(y * 0.70710678118654752f));
    u16 hi, lo; split2(ge, hi, lo);
    g2[row * 768 + o] = hi;
    g2[row * 768 + 384 + o] = lo;
}

// ---------------- K5: out = bn2(g @ fc2_w^T + fc2_b) + x, MFMA, no LDS ----------------
__global__ __launch_bounds__(256, 2) void k5_fc2_bn2(
    const u16* __restrict__ g2, const u16* __restrict__ w5,
    const float* __restrict__ fc2b, const float* __restrict__ cst,
    const float* __restrict__ x, float* __restrict__ out)
{
    int bx = blockIdx.x;
    int c0 = blockIdx.y * 32;
    int b  = bx / 49;
    int n0 = (bx % 49) * 64;
    int r0 = bx * 64;
    int t = threadIdx.x, lane = t & 63, w = t >> 6;
    int col16 = lane & 15, g = lane >> 4;

    const u16* ar = g2 + (size_t)(r0 + w * 16 + col16) * 768;
    const u16* br = w5 + (size_t)(c0 + col16) * 768 + g * 8;
    f32x4 acc0 = {0.f, 0.f, 0.f, 0.f};
    f32x4 acc1 = {0.f, 0.f, 0.f, 0.f};
    #pragma unroll
    for (int kh = 0; kh < 2; ++kh) {
        s16x8 a_hi[6], a_lo[6];
        #pragma unroll
        for (int ko = 0; ko < 6; ++ko) {
            a_hi[ko] = *reinterpret_cast<const s16x8*>(ar + (kh * 6 + ko) * 32 + g * 8);
            a_lo[ko] = *reinterpret_cast<const s16x8*>(ar + 384 + (kh * 6 + ko) * 32 + g * 8);
        }
        #pragma unroll
        for (int ko = 0; ko < 6; ++ko) {
            int kk = (kh * 6 + ko) * 32;
            s16x8 b0h = *reinterpret_cast<const s16x8*>(br + kk);
            s16x8 b0l = *reinterpret_cast<const s16x8*>(br + 384 + kk);
            s16x8 b1h = *reinterpret_cast<const s16x8*>(br + 16 * 768 + kk);
            s16x8 b1l = *reinterpret_cast<const s16x8*>(br + 16 * 768 + 384 + kk);
            acc0 = __builtin_amdgcn_mfma_f32_16x16x32_bf16(a_hi[ko], b0h, acc0, 0, 0, 0);
            acc0 = __builtin_amdgcn_mfma_f32_16x16x32_bf16(a_hi[ko], b0l, acc0, 0, 0, 0);
            acc0 = __builtin_amdgcn_mfma_f32_16x16x32_bf16(a_lo[ko], b0h, acc0, 0, 0, 0);
            acc1 = __builtin_amdgcn_mfma_f32_16x16x32_bf16(a_hi[ko], b1h, acc1, 0, 0, 0);
            acc1 = __builtin_amdgcn_mfma_f32_16x16x32_bf16(a_hi[ko], b1l, acc1, 0, 0, 0);
            acc1 = __builtin_amdgcn_mfma_f32_16x16x32_bf16(a_lo[ko], b1h, acc1, 0, 0, 0);
        }
    }
    #pragma unroll
    for (int oq = 0; oq < 2; ++oq) {
        int c = c0 + oq * 16 + col16;
        float s2 = cst[1152 + c], sh2 = cst[1344 + c], bz = fc2b[c];
        #pragma unroll
        for (int i = 0; i < 4; ++i) {
            int n = n0 + w * 16 + g * 4 + i;
            size_t a = (size_t)b * C_DIM * N_PIX + (size_t)c * N_PIX + n;
            float v = (oq ? acc1[i] : acc0[i]) + bz;
            out[a] = v * s2 + sh2 + x[a];
        }
    }
}

extern "C" void kernel_launch(void* const* d_in, const int* in_sizes, int n_in,
                              void* d_out, int out_size, void* d_ws, size_t ws_size,
                              hipStream_t stream)
{
    const float* x      = (const float*)d_in[0];
    const float* fc1_w  = (const float*)d_in[1];
    const float* fc1_b  = (const float*)d_in[2];
    const float* bn1_g  = (const float*)d_in[3];
    const float* bn1_b  = (const float*)d_in[4];
    const float* bn1_m  = (const float*)d_in[5];
    const float* bn1_v  = (const float*)d_in[6];
    const float* gcn_w  = (const float*)d_in[7];
    const float* gcn_b  = (const float*)d_in[8];
    const float* bng_g  = (const float*)d_in[9];
    const float* bng_b  = (const float*)d_in[10];
    const float* bng_m  = (const float*)d_in[11];
    const float* bng_v  = (const float*)d_in[12];
    const float* fc2_w  = (const float*)d_in[13];
    const float* fc2_b  = (const float*)d_in[14];
    const float* bn2_g  = (const float*)d_in[15];
    const float* bn2_b  = (const float*)d_in[16];
    const float* bn2_m  = (const float*)d_in[17];
    const float* bn2_v  = (const float*)d_in[18];
    float* out = (float*)d_out;

    float* ws  = (float*)d_ws;
    float* h   = ws + OFF_H;
    float* sq  = ws + OFF_SQ;
    u16*   h2  = (u16*)(ws + OFF_H2);
    u16*   g2  = (u16*)(ws + OFF_G2);
    u16*   Pbf = (u16*)(ws + OFF_PBF);
    u16*   Qbf = (u16*)(ws + OFF_QBF);
    u16*   wc2 = (u16*)(ws + OFF_WC2);
    u16*   w5  = (u16*)(ws + OFF_W5);
    float* cst = ws + OFF_CST;
    int*   idx = (int*)(ws + OFF_IDX);
    unsigned long long* pl = (unsigned long long*)(ws + OFF_PL);

    k_prep<<<867, 256, 0, stream>>>(gcn_w, fc2_w,
                                    bn1_g, bn1_b, bn1_m, bn1_v,
                                    bng_g, bng_b, bng_m, bng_v,
                                    bn2_g, bn2_b, bn2_m, bn2_v, wc2, w5, cst);
    k1_fc1_bn1<<<dim3(196, 3), 256, 0, stream>>>(x, fc1_w, fc1_b, cst, h);
    k_sq<<<49, 256, 0, stream>>>(h, sq);
    k_split<<<2352, 256, 0, stream>>>(h, h2);
    k3_knn<<<1372, 128, 0, stream>>>(h2, sq, pl);
    k3b_merge<<<49, 256, 0, stream>>>(pl, idx);
    k2_pq<<<dim3(196, 24), 256, 0, stream>>>(h2, wc2, gcn_b, Pbf, Qbf);
    k4_agg<<<12544, 384, 0, stream>>>(Pbf, Qbf, idx, cst, g2);
    k5_fc2_bn2<<<dim3(196, 6), 256, 0, stream>>>(g2, w5, fc2_b, cst, x, out);
}

// Round 9
// 433.972 us; speedup vs baseline: 1.5606x; 1.5606x over previous
//
#include <hip/hip_runtime.h>
#include <math.h>

#define N_PIX 3136
#define C_DIM 192
#define HID_DIM 384
#define KNN 9
#define EPS_BN 1e-5f

typedef __attribute__((ext_vector_type(4))) float f32x4;
typedef __attribute__((ext_vector_type(8))) short s16x8;
typedef unsigned short u16;

// ---------------- workspace layout (float units) ----------------
static const size_t OFF_H   = 0;            // h fp32: 12544*192
static const size_t OFF_SQ  = 2408448;      // sq: 12544
static const size_t OFF_H2  = 2420992;      // h2 u16 [hi192|lo192]
static const size_t OFF_G2  = 0;            // g2 u16 overlay (h/sq/h2 dead after k2)
static const size_t OFF_PBF = 4829440;      // P bf16
static const size_t OFF_QBF = 7237888;      // Q bf16
static const size_t OFF_WC2 = 9646336;      // wc2 u16 768*384
static const size_t OFF_W5  = 9793792;      // w5 u16 192*768
static const size_t OFF_CST = 9867520;      // 1536 f
static const size_t OFF_IDX = 9869056;      // 112,896 int
static const size_t OFF_PL  = 9981952;      // 12544*7*9 u64

__device__ inline u16 f2bf_rn(float x) {
    unsigned u = __float_as_uint(x);
    unsigned r = u + 0x7fffu + ((u >> 16) & 1u);
    return (u16)(r >> 16);
}
__device__ inline float bf2f(u16 v) { return __uint_as_float((unsigned)v << 16); }
__device__ inline void split2(float x, u16& hi, u16& lo) {
    hi = f2bf_rn(x);
    lo = f2bf_rn(x - bf2f(hi));
}

// ---------------- prep: wc2/w5 bf16 splits + BN scale/shift ----------------
__global__ void k_prep(const float* __restrict__ gcn_w, const float* __restrict__ fc2_w,
                       const float* __restrict__ bn1_g, const float* __restrict__ bn1_b,
                       const float* __restrict__ bn1_m, const float* __restrict__ bn1_v,
                       const float* __restrict__ bng_g, const float* __restrict__ bng_b,
                       const float* __restrict__ bng_m, const float* __restrict__ bng_v,
                       const float* __restrict__ bn2_g, const float* __restrict__ bn2_b,
                       const float* __restrict__ bn2_m, const float* __restrict__ bn2_v,
                       u16* __restrict__ wc2, u16* __restrict__ w5, float* __restrict__ cst)
{
    int t = blockIdx.x * 256 + threadIdx.x;
    if (t < 768 * 192) {
        int o = t / 192, c = t % 192;
        float v = (o < 384) ? gcn_w[o * 384 + c] - gcn_w[o * 384 + 192 + c]
                            : gcn_w[(o - 384) * 384 + 192 + c];
        u16 hi, lo; split2(v, hi, lo);
        wc2[(size_t)o * 384 + c] = hi;
        wc2[(size_t)o * 384 + 192 + c] = lo;
    } else if (t < 768 * 192 + 192 * 384) {
        int u = t - 768 * 192;
        int c = u / 384, k = u % 384;
        u16 hi, lo; split2(fc2_w[(size_t)c * 384 + k], hi, lo);
        w5[(size_t)c * 768 + k] = hi;
        w5[(size_t)c * 768 + 384 + k] = lo;
    } else if (t < 768 * 192 + 192 * 384 + 768) {
        int u = t - 768 * 192 - 192 * 384;
        if (u < 192) {
            float s = bn1_g[u] / sqrtf(bn1_v[u] + EPS_BN);
            cst[u] = s; cst[192 + u] = bn1_b[u] - bn1_m[u] * s;
        } else if (u < 576) {
            int ch = u - 192;
            float s = bng_g[ch] / sqrtf(bng_v[ch] + EPS_BN);
            cst[384 + ch] = s; cst[768 + ch] = bng_b[ch] - bng_m[ch] * s;
        } else {
            int ch = u - 576;
            float s = bn2_g[ch] / sqrtf(bn2_v[ch] + EPS_BN);
            cst[1152 + ch] = s; cst[1344 + ch] = bn2_b[ch] - bn2_m[ch] * s;
        }
    }
}

// ---------------- K1: h = bn1(xf @ fc1_w^T + fc1_b)  (fp32 VALU GEMM) ----------------
__global__ __launch_bounds__(256) void k1_fc1_bn1(
    const float* __restrict__ x, const float* __restrict__ w,
    const float* __restrict__ bias, const float* __restrict__ cst,
    float* __restrict__ h)
{
    __shared__ float As[32][64];
    __shared__ float Bs[32][64];
    int bx = blockIdx.x;
    int o0 = blockIdx.y * 64;
    int b  = bx / 49;
    int n0 = (bx % 49) * 64;
    const float* xb = x + (size_t)b * C_DIM * N_PIX;
    int t = threadIdx.x;
    int tx = t & 15, ty = t >> 4;
    float acc[4][4] = {};
    for (int kc = 0; kc < 6; ++kc) {
        #pragma unroll
        for (int p = 0; p < 2; ++p) {
            int idx = t + p * 256;
            int kk = idx >> 4, j4 = idx & 15;
            float4 v = *reinterpret_cast<const float4*>(xb + (size_t)(kc * 32 + kk) * N_PIX + n0 + j4 * 4);
            *reinterpret_cast<float4*>(&As[kk][j4 * 4]) = v;
        }
        #pragma unroll
        for (int p = 0; p < 2; ++p) {
            int idx = t + p * 256;
            int oo = idx >> 3, c4 = idx & 7;
            float4 v = *reinterpret_cast<const float4*>(w + (size_t)(o0 + oo) * C_DIM + kc * 32 + c4 * 4);
            Bs[c4 * 4 + 0][oo] = v.x; Bs[c4 * 4 + 1][oo] = v.y;
            Bs[c4 * 4 + 2][oo] = v.z; Bs[c4 * 4 + 3][oo] = v.w;
        }
        __syncthreads();
        #pragma unroll
        for (int kk = 0; kk < 32; ++kk) {
            float4 av = *reinterpret_cast<const float4*>(&As[kk][ty * 4]);
            float4 bv = *reinterpret_cast<const float4*>(&Bs[kk][tx * 4]);
            float a[4] = {av.x, av.y, av.z, av.w};
            float bb[4] = {bv.x, bv.y, bv.z, bv.w};
            #pragma unroll
            for (int i = 0; i < 4; ++i)
                #pragma unroll
                for (int j = 0; j < 4; ++j) acc[i][j] += a[i] * bb[j];
        }
        __syncthreads();
    }
    #pragma unroll
    for (int i = 0; i < 4; ++i) {
        int n = n0 + ty * 4 + i;
        size_t r = (size_t)b * N_PIX + n;
        float vals[4];
        #pragma unroll
        for (int j = 0; j < 4; ++j) {
            int o = o0 + tx * 4 + j;
            vals[j] = (acc[i][j] + bias[o]) * cst[o] + cst[192 + o];
        }
        *reinterpret_cast<float4*>(h + r * C_DIM + o0 + tx * 4) =
            make_float4(vals[0], vals[1], vals[2], vals[3]);
    }
}

// ---------------- K1b: sq[r] = sum_c h[r][c]^2 ----------------
__global__ __launch_bounds__(256) void k_sq(const float* __restrict__ h, float* __restrict__ sq)
{
    int r = blockIdx.x * 256 + threadIdx.x;
    const float* hr = h + (size_t)r * C_DIM;
    float s = 0.f;
    #pragma unroll
    for (int c = 0; c < C_DIM; c += 4) {
        float4 v = *reinterpret_cast<const float4*>(hr + c);
        s += v.x * v.x + v.y * v.y + v.z * v.z + v.w * v.w;
    }
    sq[r] = s;
}

// ---------------- K1c: split h into bf16 hi|lo ----------------
__global__ __launch_bounds__(256) void k_split(const float* __restrict__ h, u16* __restrict__ h2)
{
    int t = blockIdx.x * 256 + threadIdx.x;
    int base = t * 4;
    int r = base / C_DIM, c = base % C_DIM;
    float4 v = *reinterpret_cast<const float4*>(h + base);
    float f[4] = {v.x, v.y, v.z, v.w};
    u16* dst = h2 + (size_t)r * 384 + c;
    #pragma unroll
    for (int j = 0; j < 4; ++j) {
        u16 hi, lo; split2(f[j], hi, lo);
        dst[j] = hi; dst[192 + j] = lo;
    }
}

// ---------------- K3: MFMA dist (round-5 loop) + decoupled wave-private select ----------------
// grid 1372 (4b*49strip*7mc), 256 thr (4 waves). Wave owns 16 n-rows (A-frags 48 VGPR).
// m-step 32: B tile [32][408 u16] in LDS (stride 102 dwords == 6 mod 32 -> reads spread).
// Epilogue: fmaf(-2,dot,sqm) -> wave-private key tile [32m][20 f32] (b128 writes, no barrier);
// lane owns (row=lane>>2, mseg=lane&3), scans 8 keys/step -> single cand[9] (18 VGPR).
#define BSTR 408
__global__ __launch_bounds__(256) void k3_knn(
    const u16* __restrict__ h2, const float* __restrict__ sq,
    unsigned long long* __restrict__ pl)
{
    __shared__ u16 Bs[32 * BSTR];        // 26112 B
    __shared__ float keyt[4][32 * 20];   // 10240 B
    int bx = blockIdx.x;
    int b = bx / 343, rem = bx % 343;
    int strip = rem / 7, mc = rem % 7;
    int n0 = strip * 64;
    const u16* hb = h2 + (size_t)b * N_PIX * 384;
    const float* sqb = sq + (size_t)b * N_PIX;
    int t = threadIdx.x;
    int lane = t & 63, w = t >> 6;
    int col16 = lane & 15, g = lane >> 4;

    // A fragments: row = n0 + w*16 + col16, k = ko*32 + g*8 (+192 for lo)
    s16x8 a_hi[6], a_lo[6];
    {
        const u16* ar = hb + (size_t)(n0 + w * 16 + col16) * 384;
        #pragma unroll
        for (int ko = 0; ko < 6; ++ko) {
            a_hi[ko] = *reinterpret_cast<const s16x8*>(ar + ko * 32 + g * 8);
            a_lo[ko] = *reinterpret_cast<const s16x8*>(ar + 192 + ko * 32 + g * 8);
        }
    }

    int srow = lane >> 2, mseg = lane & 3;         // select ownership
    float sqn_r = sqb[n0 + w * 16 + srow];
    unsigned long long cand[KNN];
    #pragma unroll
    for (int q = 0; q < KNN; ++q) cand[q] = ~0ull;

    float* kt = keyt[w];
    int srow_stage = t & 31, half = t >> 5;        // staging role: 2-way LDS writes

    for (int step = 0; step < 14; ++step) {
        int m0 = mc * 448 + step * 32;
        __syncthreads();
        {   // stage 32 m-rows x 384 u16
            const u16* src = hb + (size_t)(m0 + srow_stage) * 384 + half * 48;
            u16* dst = Bs + srow_stage * BSTR + half * 48;
            #pragma unroll
            for (int c = 0; c < 6; ++c)
                *reinterpret_cast<s16x8*>(dst + c * 8) =
                    *reinterpret_cast<const s16x8*>(src + c * 8);
        }
        __syncthreads();

        f32x4 acc0 = {0.f, 0.f, 0.f, 0.f};
        f32x4 acc1 = {0.f, 0.f, 0.f, 0.f};
        const u16* b0 = Bs + col16 * BSTR + g * 8;
        const u16* b1 = Bs + (16 + col16) * BSTR + g * 8;
        #pragma unroll
        for (int ko = 0; ko < 6; ++ko) {
            s16x8 b0h = *reinterpret_cast<const s16x8*>(b0 + ko * 32);
            s16x8 b0l = *reinterpret_cast<const s16x8*>(b0 + 192 + ko * 32);
            s16x8 b1h = *reinterpret_cast<const s16x8*>(b1 + ko * 32);
            s16x8 b1l = *reinterpret_cast<const s16x8*>(b1 + 192 + ko * 32);
            acc0 = __builtin_amdgcn_mfma_f32_16x16x32_bf16(a_hi[ko], b0h, acc0, 0, 0, 0);
            acc0 = __builtin_amdgcn_mfma_f32_16x16x32_bf16(a_hi[ko], b0l, acc0, 0, 0, 0);
            acc0 = __builtin_amdgcn_mfma_f32_16x16x32_bf16(a_lo[ko], b0h, acc0, 0, 0, 0);
            acc1 = __builtin_amdgcn_mfma_f32_16x16x32_bf16(a_hi[ko], b1h, acc1, 0, 0, 0);
            acc1 = __builtin_amdgcn_mfma_f32_16x16x32_bf16(a_hi[ko], b1l, acc1, 0, 0, 0);
            acc1 = __builtin_amdgcn_mfma_f32_16x16x32_bf16(a_lo[ko], b1h, acc1, 0, 0, 0);
        }

        // write partial keys: rows g*4+i, cols {col16, 16+col16}
        float sqm0 = sqb[m0 + col16];
        float sqm1 = sqb[m0 + 16 + col16];
        f32x4 k0, k1;
        #pragma unroll
        for (int i = 0; i < 4; ++i) {
            k0[i] = fmaf(-2.0f, acc0[i], sqm0);
            k1[i] = fmaf(-2.0f, acc1[i], sqm1);
        }
        *reinterpret_cast<f32x4*>(kt + col16 * 20 + g * 4) = k0;
        *reinterpret_cast<f32x4*>(kt + (16 + col16) * 20 + g * 4) = k1;
        asm volatile("" ::: "memory");   // order LDS writes before same-wave reads

        // select: lane scans its 8 m-values for its row
        #pragma unroll
        for (int j = 0; j < 8; ++j) {
            int ml = mseg * 8 + j;
            float dist = kt[ml * 20 + srow] + sqn_r;
            int m = m0 + ml;
            unsigned u = __float_as_uint(dist);
            u = (u & 0x80000000u) ? ~u : (u | 0x80000000u);
            unsigned long long key = ((unsigned long long)u << 32) | (unsigned)m;
            if (key < cand[KNN - 1]) {
                cand[KNN - 1] = key;
                #pragma unroll
                for (int q = KNN - 1; q > 0; --q) {
                    unsigned long long lo2 = cand[q - 1], hi2 = cand[q];
                    if (hi2 < lo2) { cand[q - 1] = hi2; cand[q] = lo2; }
                }
            }
        }
    }

    // merge 4 partial lists per row (lanes 4*srow..+3), write sorted 9
    {
        int n = n0 + w * 16 + srow;
        size_t rowg = (size_t)b * N_PIX + n;
        for (int r = 0; r < KNN; ++r) {
            unsigned long long my = cand[0];
            unsigned long long gm = my;
            unsigned long long o1 = __shfl_xor(gm, 1); if (o1 < gm) gm = o1;
            unsigned long long o2 = __shfl_xor(gm, 2); if (o2 < gm) gm = o2;
            if (gm == my) {
                #pragma unroll
                for (int q = 0; q < KNN - 1; ++q) cand[q] = cand[q + 1];
                cand[KNN - 1] = ~0ull;
            }
            if (mseg == 0)
                pl[(rowg * 7 + mc) * KNN + r] = gm;
        }
    }
}

// ---------------- K3b: merge 7 sorted partial lists -> final idx ----------------
__global__ __launch_bounds__(256) void k3b_merge(
    const unsigned long long* __restrict__ pl, int* __restrict__ idxout)
{
    int r = blockIdx.x * 256 + threadIdx.x;
    const unsigned long long* base = pl + (size_t)r * 63;
    unsigned long long list[KNN];
    #pragma unroll
    for (int q = 0; q < KNN; ++q) list[q] = ~0ull;
    for (int c = 0; c < 63; ++c) {
        unsigned long long k = base[c];
        if (k < list[KNN - 1]) {
            list[KNN - 1] = k;
            #pragma unroll
            for (int q = KNN - 1; q > 0; --q) {
                unsigned long long lo = list[q - 1], hi = list[q];
                if (hi < lo) { list[q - 1] = hi; list[q] = lo; }
            }
        }
    }
    #pragma unroll
    for (int q = 0; q < KNN; ++q)
        idxout[(size_t)r * KNN + q] = (int)(list[q] & 0xffffffffu);
}

// ---------------- K2: P,Q = h @ Wc^T (+bias) -> bf16, MFMA, no LDS ----------------
__global__ __launch_bounds__(256, 2) void k2_pq(
    const u16* __restrict__ h2, const u16* __restrict__ wc2,
    const float* __restrict__ gcnb, u16* __restrict__ Pbf, u16* __restrict__ Qbf)
{
    int r0 = blockIdx.x * 64;
    int o0 = blockIdx.y * 32;
    int t = threadIdx.x, lane = t & 63, w = t >> 6;
    int col16 = lane & 15, g = lane >> 4;

    s16x8 a_hi[6], a_lo[6];
    {
        const u16* ar = h2 + (size_t)(r0 + w * 16 + col16) * 384;
        #pragma unroll
        for (int ko = 0; ko < 6; ++ko) {
            a_hi[ko] = *reinterpret_cast<const s16x8*>(ar + ko * 32 + g * 8);
            a_lo[ko] = *reinterpret_cast<const s16x8*>(ar + 192 + ko * 32 + g * 8);
        }
    }
    const u16* br = wc2 + (size_t)(o0 + col16) * 384 + g * 8;
    f32x4 acc0 = {0.f, 0.f, 0.f, 0.f};
    f32x4 acc1 = {0.f, 0.f, 0.f, 0.f};
    #pragma unroll
    for (int ko = 0; ko < 6; ++ko) {
        s16x8 b0h = *reinterpret_cast<const s16x8*>(br + ko * 32);
        s16x8 b0l = *reinterpret_cast<const s16x8*>(br + 192 + ko * 32);
        s16x8 b1h = *reinterpret_cast<const s16x8*>(br + 16 * 384 + ko * 32);
        s16x8 b1l = *reinterpret_cast<const s16x8*>(br + 16 * 384 + 192 + ko * 32);
        acc0 = __builtin_amdgcn_mfma_f32_16x16x32_bf16(a_hi[ko], b0h, acc0, 0, 0, 0);
        acc0 = __builtin_amdgcn_mfma_f32_16x16x32_bf16(a_hi[ko], b0l, acc0, 0, 0, 0);
        acc0 = __builtin_amdgcn_mfma_f32_16x16x32_bf16(a_lo[ko], b0h, acc0, 0, 0, 0);
        acc1 = __builtin_amdgcn_mfma_f32_16x16x32_bf16(a_hi[ko], b1h, acc1, 0, 0, 0);
        acc1 = __builtin_amdgcn_mfma_f32_16x16x32_bf16(a_hi[ko], b1l, acc1, 0, 0, 0);
        acc1 = __builtin_amdgcn_mfma_f32_16x16x32_bf16(a_lo[ko], b1h, acc1, 0, 0, 0);
    }
    bool isP = (o0 < HID_DIM);
    #pragma unroll
    for (int oq = 0; oq < 2; ++oq) {
        int o = o0 + oq * 16 + col16;
        float bias = isP ? gcnb[o] : 0.0f;
        #pragma unroll
        for (int i = 0; i < 4; ++i) {
            size_t r = (size_t)(r0 + w * 16 + g * 4 + i);
            float v = (oq ? acc1[i] : acc0[i]) + bias;
            u16 bv = f2bf_rn(v);
            if (isP) Pbf[r * 384 + o] = bv;
            else     Qbf[r * 384 + (o - HID_DIM)] = bv;
        }
    }
}

// ---------------- K4: g2 = split(gelu(bn_g(P + max_k Q[idx[k]]))) ----------------
__global__ __launch_bounds__(384) void k4_agg(
    const u16* __restrict__ Pbf, const u16* __restrict__ Qbf,
    const int* __restrict__ idx, const float* __restrict__ cst,
    u16* __restrict__ g2)
{
    int blk = blockIdx.x;
    int b = blk / N_PIX;
    size_t row = (size_t)blk;
    const int* id = idx + row * KNN;
    int o = threadIdx.x;
    const u16* Qb = Qbf + (size_t)b * N_PIX * 384;
    float v = -INFINITY;
    #pragma unroll
    for (int k = 0; k < KNN; ++k)
        v = fmaxf(v, bf2f(Qb[(size_t)id[k] * 384 + o]));
    float p = bf2f(Pbf[row * 384 + o]);
    float y = (p + v) * cst[384 + o] + cst[768 + o];
    float ge = 0.5f * y * (1.0f + erff(y * 0.70710678118654752f));
    u16 hi, lo; split2(ge, hi, lo);
    g2[row * 768 + o] = hi;
    g2[row * 768 + 384 + o] = lo;
}

// ---------------- K5: out = bn2(g @ fc2_w^T + fc2_b) + x, MFMA, no LDS ----------------
__global__ __launch_bounds__(256, 2) void k5_fc2_bn2(
    const u16* __restrict__ g2, const u16* __restrict__ w5,
    const float* __restrict__ fc2b, const float* __restrict__ cst,
    const float* __restrict__ x, float* __restrict__ out)
{
    int bx = blockIdx.x;
    int c0 = blockIdx.y * 32;
    int b  = bx / 49;
    int n0 = (bx % 49) * 64;
    int r0 = bx * 64;
    int t = threadIdx.x, lane = t & 63, w = t >> 6;
    int col16 = lane & 15, g = lane >> 4;

    const u16* ar = g2 + (size_t)(r0 + w * 16 + col16) * 768;
    const u16* br = w5 + (size_t)(c0 + col16) * 768 + g * 8;
    f32x4 acc0 = {0.f, 0.f, 0.f, 0.f};
    f32x4 acc1 = {0.f, 0.f, 0.f, 0.f};
    #pragma unroll
    for (int kh = 0; kh < 2; ++kh) {
        s16x8 a_hi[6], a_lo[6];
        #pragma unroll
        for (int ko = 0; ko < 6; ++ko) {
            a_hi[ko] = *reinterpret_cast<const s16x8*>(ar + (kh * 6 + ko) * 32 + g * 8);
            a_lo[ko] = *reinterpret_cast<const s16x8*>(ar + 384 + (kh * 6 + ko) * 32 + g * 8);
        }
        #pragma unroll
        for (int ko = 0; ko < 6; ++ko) {
            int kk = (kh * 6 + ko) * 32;
            s16x8 b0h = *reinterpret_cast<const s16x8*>(br + kk);
            s16x8 b0l = *reinterpret_cast<const s16x8*>(br + 384 + kk);
            s16x8 b1h = *reinterpret_cast<const s16x8*>(br + 16 * 768 + kk);
            s16x8 b1l = *reinterpret_cast<const s16x8*>(br + 16 * 768 + 384 + kk);
            acc0 = __builtin_amdgcn_mfma_f32_16x16x32_bf16(a_hi[ko], b0h, acc0, 0, 0, 0);
            acc0 = __builtin_amdgcn_mfma_f32_16x16x32_bf16(a_hi[ko], b0l, acc0, 0, 0, 0);
            acc0 = __builtin_amdgcn_mfma_f32_16x16x32_bf16(a_lo[ko], b0h, acc0, 0, 0, 0);
            acc1 = __builtin_amdgcn_mfma_f32_16x16x32_bf16(a_hi[ko], b1h, acc1, 0, 0, 0);
            acc1 = __builtin_amdgcn_mfma_f32_16x16x32_bf16(a_hi[ko], b1l, acc1, 0, 0, 0);
            acc1 = __builtin_amdgcn_mfma_f32_16x16x32_bf16(a_lo[ko], b1h, acc1, 0, 0, 0);
        }
    }
    #pragma unroll
    for (int oq = 0; oq < 2; ++oq) {
        int c = c0 + oq * 16 + col16;
        float s2 = cst[1152 + c], sh2 = cst[1344 + c], bz = fc2b[c];
        #pragma unroll
        for (int i = 0; i < 4; ++i) {
            int n = n0 + w * 16 + g * 4 + i;
            size_t a = (size_t)b * C_DIM * N_PIX + (size_t)c * N_PIX + n;
            float v = (oq ? acc1[i] : acc0[i]) + bz;
            out[a] = v * s2 + sh2 + x[a];
        }
    }
}

extern "C" void kernel_launch(void* const* d_in, const int* in_sizes, int n_in,
                              void* d_out, int out_size, void* d_ws, size_t ws_size,
                              hipStream_t stream)
{
    const float* x      = (const float*)d_in[0];
    const float* fc1_w  = (const float*)d_in[1];
    const float* fc1_b  = (const float*)d_in[2];
    const float* bn1_g  = (const float*)d_in[3];
    const float* bn1_b  = (const float*)d_in[4];
    const float* bn1_m  = (const float*)d_in[5];
    const float* bn1_v  = (const float*)d_in[6];
    const float* gcn_w  = (const float*)d_in[7];
    const float* gcn_b  = (const float*)d_in[8];
    const float* bng_g  = (const float*)d_in[9];
    const float* bng_b  = (const float*)d_in[10];
    const float* bng_m  = (const float*)d_in[11];
    const float* bng_v  = (const float*)d_in[12];
    const float* fc2_w  = (const float*)d_in[13];
    const float* fc2_b  = (const float*)d_in[14];
    const float* bn2_g  = (const float*)d_in[15];
    const float* bn2_b  = (const float*)d_in[16];
    const float* bn2_m  = (const float*)d_in[17];
    const float* bn2_v  = (const float*)d_in[18];
    float* out = (float*)d_out;

    float* ws  = (float*)d_ws;
    float* h   = ws + OFF_H;
    float* sq  = ws + OFF_SQ;
    u16*   h2  = (u16*)(ws + OFF_H2);
    u16*   g2  = (u16*)(ws + OFF_G2);
    u16*   Pbf = (u16*)(ws + OFF_PBF);
    u16*   Qbf = (u16*)(ws + OFF_QBF);
    u16*   wc2 = (u16*)(ws + OFF_WC2);
    u16*   w5  = (u16*)(ws + OFF_W5);
    float* cst = ws + OFF_CST;
    int*   idx = (int*)(ws + OFF_IDX);
    unsigned long long* pl = (unsigned long long*)(ws + OFF_PL);

    k_prep<<<867, 256, 0, stream>>>(gcn_w, fc2_w,
                                    bn1_g, bn1_b, bn1_m, bn1_v,
                                    bng_g, bng_b, bng_m, bng_v,
                                    bn2_g, bn2_b, bn2_m, bn2_v, wc2, w5, cst);
    k1_fc1_bn1<<<dim3(196, 3), 256, 0, stream>>>(x, fc1_w, fc1_b, cst, h);
    k_sq<<<49, 256, 0, stream>>>(h, sq);
    k_split<<<2352, 256, 0, stream>>>(h, h2);
    k3_knn<<<1372, 256, 0, stream>>>(h2, sq, pl);
    k3b_merge<<<49, 256, 0, stream>>>(pl, idx);
    k2_pq<<<dim3(196, 24), 256, 0, stream>>>(h2, wc2, gcn_b, Pbf, Qbf);
    k4_agg<<<12544, 384, 0, stream>>>(Pbf, Qbf, idx, cst, g2);
    k5_fc2_bn2<<<dim3(196, 6), 256, 0, stream>>>(g2, w5, fc2_b, cst, x, out);
}

// Round 10
// 404.259 us; speedup vs baseline: 1.6754x; 1.0735x over previous
//
#include <hip/hip_runtime.h>
#include <math.h>

#define N_PIX 3136
#define C_DIM 192
#define HID_DIM 384
#define KNN 9
#define EPS_BN 1e-5f

typedef __attribute__((ext_vector_type(4))) float f32x4;
typedef __attribute__((ext_vector_type(8))) short s16x8;
typedef unsigned short u16;

// ---------------- workspace layout (float units) ----------------
static const size_t OFF_SQP = 0;            // sqp fp32 3*12544 (overlaid by g2 later)
static const size_t OFF_SQ  = 2408448;      // sq: 12544
static const size_t OFF_H2  = 2420992;      // h2 u16 [hi192|lo192]: 12544*384 u16
static const size_t OFF_G2  = 0;            // g2 u16 12544*768 overlay (sqp/sq/h2 dead by k4)
static const size_t OFF_PBF = 4829440;      // P bf16
static const size_t OFF_QBF = 7237888;      // Q bf16
static const size_t OFF_WC2 = 9646336;      // wc2 u16 768*384
static const size_t OFF_W5  = 9793792;      // w5 u16 192*768
static const size_t OFF_CST = 9867520;      // 1536 f
static const size_t OFF_IDX = 9869056;      // 112,896 int
static const size_t OFF_PL  = 9981952;      // 12544*7*9 u64

__device__ inline u16 f2bf_rn(float x) {
    unsigned u = __float_as_uint(x);
    unsigned r = u + 0x7fffu + ((u >> 16) & 1u);
    return (u16)(r >> 16);
}
__device__ inline float bf2f(u16 v) { return __uint_as_float((unsigned)v << 16); }
__device__ inline void split2(float x, u16& hi, u16& lo) {
    hi = f2bf_rn(x);
    lo = f2bf_rn(x - bf2f(hi));
}
__device__ inline void gload16(const void* g, void* l) {
    __builtin_amdgcn_global_load_lds(
        (const __attribute__((address_space(1))) unsigned int*)g,
        (__attribute__((address_space(3))) unsigned int*)l, 16, 0, 0);
}

// ---------------- prep: wc2/w5 bf16 splits + BN scale/shift ----------------
__global__ void k_prep(const float* __restrict__ gcn_w, const float* __restrict__ fc2_w,
                       const float* __restrict__ bn1_g, const float* __restrict__ bn1_b,
                       const float* __restrict__ bn1_m, const float* __restrict__ bn1_v,
                       const float* __restrict__ bng_g, const float* __restrict__ bng_b,
                       const float* __restrict__ bng_m, const float* __restrict__ bng_v,
                       const float* __restrict__ bn2_g, const float* __restrict__ bn2_b,
                       const float* __restrict__ bn2_m, const float* __restrict__ bn2_v,
                       u16* __restrict__ wc2, u16* __restrict__ w5, float* __restrict__ cst)
{
    int t = blockIdx.x * 256 + threadIdx.x;
    if (t < 768 * 192) {
        int o = t / 192, c = t % 192;
        float v = (o < 384) ? gcn_w[o * 384 + c] - gcn_w[o * 384 + 192 + c]
                            : gcn_w[(o - 384) * 384 + 192 + c];
        u16 hi, lo; split2(v, hi, lo);
        wc2[(size_t)o * 384 + c] = hi;
        wc2[(size_t)o * 384 + 192 + c] = lo;
    } else if (t < 768 * 192 + 192 * 384) {
        int u = t - 768 * 192;
        int c = u / 384, k = u % 384;
        u16 hi, lo; split2(fc2_w[(size_t)c * 384 + k], hi, lo);
        w5[(size_t)c * 768 + k] = hi;
        w5[(size_t)c * 768 + 384 + k] = lo;
    } else if (t < 768 * 192 + 192 * 384 + 768) {
        int u = t - 768 * 192 - 192 * 384;
        if (u < 192) {
            float s = bn1_g[u] / sqrtf(bn1_v[u] + EPS_BN);
            cst[u] = s; cst[192 + u] = bn1_b[u] - bn1_m[u] * s;
        } else if (u < 576) {
            int ch = u - 192;
            float s = bng_g[ch] / sqrtf(bng_v[ch] + EPS_BN);
            cst[384 + ch] = s; cst[768 + ch] = bng_b[ch] - bng_m[ch] * s;
        } else {
            int ch = u - 576;
            float s = bn2_g[ch] / sqrtf(bn2_v[ch] + EPS_BN);
            cst[1152 + ch] = s; cst[1344 + ch] = bn2_b[ch] - bn2_m[ch] * s;
        }
    }
}

// ---------------- K1: h2 = split(bn1(xf @ fc1_w^T + fc1_b)), sqp partials ----------------
__global__ __launch_bounds__(256) void k1_fc1_bn1(
    const float* __restrict__ x, const float* __restrict__ w,
    const float* __restrict__ bias, const float* __restrict__ cst,
    u16* __restrict__ h2, float* __restrict__ sqp)
{
    __shared__ float As[32][64];
    __shared__ float Bs[32][64];
    int bx = blockIdx.x;
    int oy = blockIdx.y;
    int o0 = oy * 64;
    int b  = bx / 49;
    int n0 = (bx % 49) * 64;
    const float* xb = x + (size_t)b * C_DIM * N_PIX;
    int t = threadIdx.x;
    int tx = t & 15, ty = t >> 4;
    float acc[4][4] = {};
    for (int kc = 0; kc < 6; ++kc) {
        #pragma unroll
        for (int p = 0; p < 2; ++p) {
            int idx = t + p * 256;
            int kk = idx >> 4, j4 = idx & 15;
            float4 v = *reinterpret_cast<const float4*>(xb + (size_t)(kc * 32 + kk) * N_PIX + n0 + j4 * 4);
            *reinterpret_cast<float4*>(&As[kk][j4 * 4]) = v;
        }
        #pragma unroll
        for (int p = 0; p < 2; ++p) {
            int idx = t + p * 256;
            int oo = idx >> 3, c4 = idx & 7;
            float4 v = *reinterpret_cast<const float4*>(w + (size_t)(o0 + oo) * C_DIM + kc * 32 + c4 * 4);
            Bs[c4 * 4 + 0][oo] = v.x; Bs[c4 * 4 + 1][oo] = v.y;
            Bs[c4 * 4 + 2][oo] = v.z; Bs[c4 * 4 + 3][oo] = v.w;
        }
        __syncthreads();
        #pragma unroll
        for (int kk = 0; kk < 32; ++kk) {
            float4 av = *reinterpret_cast<const float4*>(&As[kk][ty * 4]);
            float4 bv = *reinterpret_cast<const float4*>(&Bs[kk][tx * 4]);
            float a[4] = {av.x, av.y, av.z, av.w};
            float bb[4] = {bv.x, bv.y, bv.z, bv.w};
            #pragma unroll
            for (int i = 0; i < 4; ++i)
                #pragma unroll
                for (int j = 0; j < 4; ++j) acc[i][j] += a[i] * bb[j];
        }
        __syncthreads();
    }
    #pragma unroll
    for (int i = 0; i < 4; ++i) {
        int n = n0 + ty * 4 + i;
        size_t r = (size_t)b * N_PIX + n;
        ushort4 hi4, lo4;
        float s = 0.0f;
        {
            float v0 = (acc[i][0] + bias[o0 + tx * 4 + 0]) * cst[o0 + tx * 4 + 0] + cst[192 + o0 + tx * 4 + 0];
            float v1 = (acc[i][1] + bias[o0 + tx * 4 + 1]) * cst[o0 + tx * 4 + 1] + cst[192 + o0 + tx * 4 + 1];
            float v2 = (acc[i][2] + bias[o0 + tx * 4 + 2]) * cst[o0 + tx * 4 + 2] + cst[192 + o0 + tx * 4 + 2];
            float v3 = (acc[i][3] + bias[o0 + tx * 4 + 3]) * cst[o0 + tx * 4 + 3] + cst[192 + o0 + tx * 4 + 3];
            s = v0 * v0 + v1 * v1 + v2 * v2 + v3 * v3;
            u16 h_, l_;
            split2(v0, h_, l_); hi4.x = h_; lo4.x = l_;
            split2(v1, h_, l_); hi4.y = h_; lo4.y = l_;
            split2(v2, h_, l_); hi4.z = h_; lo4.z = l_;
            split2(v3, h_, l_); hi4.w = h_; lo4.w = l_;
        }
        *reinterpret_cast<ushort4*>(h2 + r * 384 + o0 + tx * 4) = hi4;
        *reinterpret_cast<ushort4*>(h2 + r * 384 + 192 + o0 + tx * 4) = lo4;
        #pragma unroll
        for (int m = 1; m < 16; m <<= 1) s += __shfl_xor(s, m);
        if (tx == 0) sqp[(size_t)oy * 12544 + r] = s;
    }
}

// ---------------- K1b: sq = sum of 3 partials (deterministic) ----------------
__global__ __launch_bounds__(256) void k_sqf(const float* __restrict__ sqp, float* __restrict__ sq)
{
    int r = blockIdx.x * 256 + threadIdx.x;
    sq[r] = sqp[r] + sqp[12544 + r] + sqp[2 * 12544 + r];
}

// ---------------- K3: MFMA dist + global_load_lds staging + decoupled select ----------------
// grid 1372 (4b*49strip*7mc), 256 thr (4 waves). Wave owns 16 n-rows (A-frags in regs).
// B tile [32][384] u16 LINEAR in LDS via global_load_lds(16B), swizzle on the GLOBAL
// source: LDS[row][q] = G[row][q^(row&7)]; reads XOR the same mask (uniform 8/bank).
// Epilogue: fmaf(-2,dot,sqm) -> wave-private key tile; lane scans 8 keys/step -> cand[9].
__global__ __launch_bounds__(256) void k3_knn(
    const u16* __restrict__ h2, const float* __restrict__ sq,
    unsigned long long* __restrict__ pl)
{
    __shared__ u16 Bs[32 * 384];         // 24576 B linear
    __shared__ float keyt[4][32 * 20];   // 10240 B
    int bx = blockIdx.x;
    int b = bx / 343, rem = bx % 343;
    int strip = rem / 7, mc = rem % 7;
    int n0 = strip * 64;
    const u16* hb = h2 + (size_t)b * N_PIX * 384;
    const float* sqb = sq + (size_t)b * N_PIX;
    int t = threadIdx.x;
    int lane = t & 63, w = t >> 6;
    int col16 = lane & 15, g = lane >> 4;

    // A fragments: row = n0 + w*16 + col16, k = ko*32 + g*8 (+192 for lo)
    s16x8 a_hi[6], a_lo[6];
    {
        const u16* ar = hb + (size_t)(n0 + w * 16 + col16) * 384;
        #pragma unroll
        for (int ko = 0; ko < 6; ++ko) {
            a_hi[ko] = *reinterpret_cast<const s16x8*>(ar + ko * 32 + g * 8);
            a_lo[ko] = *reinterpret_cast<const s16x8*>(ar + 192 + ko * 32 + g * 8);
        }
    }

    // per-lane swizzled source offsets for the 6 global_load_lds per wave
    int rowoff[6];
    {
        int lb = lane * 16;
        #pragma unroll
        for (int f = 0; f < 6; ++f) {
            int p = w * 6144 + f * 1024 + lb;     // linear LDS byte pos
            int row = p / 768;
            int q = (p % 768) >> 4;
            rowoff[f] = row * 768 + ((q ^ (row & 7)) << 4);
        }
    }

    int srow = lane >> 2, mseg = lane & 3;
    float sqn_r = sqb[n0 + w * 16 + srow];
    unsigned long long cand[KNN];
    #pragma unroll
    for (int q = 0; q < KNN; ++q) cand[q] = ~0ull;

    float* kt = keyt[w];
    const char* hbB = (const char*)hb;
    char* BsB = (char*)Bs;
    int sw = (col16 & 7) << 3;                    // u16-unit XOR mask ((c^s)*8 = (c*8)^(s*8))

    for (int step = 0; step < 14; ++step) {
        int m0 = mc * 448 + step * 32;
        size_t mbase = (size_t)m0 * 768;
        __syncthreads();
        #pragma unroll
        for (int f = 0; f < 6; ++f)
            gload16(hbB + mbase + rowoff[f], BsB + w * 6144 + f * 1024);
        __syncthreads();

        f32x4 acc0 = {0.f, 0.f, 0.f, 0.f};
        f32x4 acc1 = {0.f, 0.f, 0.f, 0.f};
        const u16* brow0 = Bs + col16 * 384;
        const u16* brow1 = Bs + (16 + col16) * 384;
        #pragma unroll
        for (int ko = 0; ko < 6; ++ko) {
            int ch = (4 * ko + g) << 3;
            int cl = (24 + 4 * ko + g) << 3;
            s16x8 b0h = *reinterpret_cast<const s16x8*>(brow0 + (ch ^ sw));
            s16x8 b0l = *reinterpret_cast<const s16x8*>(brow0 + (cl ^ sw));
            s16x8 b1h = *reinterpret_cast<const s16x8*>(brow1 + (ch ^ sw));
            s16x8 b1l = *reinterpret_cast<const s16x8*>(brow1 + (cl ^ sw));
            acc0 = __builtin_amdgcn_mfma_f32_16x16x32_bf16(a_hi[ko], b0h, acc0, 0, 0, 0);
            acc0 = __builtin_amdgcn_mfma_f32_16x16x32_bf16(a_hi[ko], b0l, acc0, 0, 0, 0);
            acc0 = __builtin_amdgcn_mfma_f32_16x16x32_bf16(a_lo[ko], b0h, acc0, 0, 0, 0);
            acc1 = __builtin_amdgcn_mfma_f32_16x16x32_bf16(a_hi[ko], b1h, acc1, 0, 0, 0);
            acc1 = __builtin_amdgcn_mfma_f32_16x16x32_bf16(a_hi[ko], b1l, acc1, 0, 0, 0);
            acc1 = __builtin_amdgcn_mfma_f32_16x16x32_bf16(a_lo[ko], b1h, acc1, 0, 0, 0);
        }

        // write partial keys: rows g*4+i, cols {col16, 16+col16}
        float sqm0 = sqb[m0 + col16];
        float sqm1 = sqb[m0 + 16 + col16];
        f32x4 k0, k1;
        #pragma unroll
        for (int i = 0; i < 4; ++i) {
            k0[i] = fmaf(-2.0f, acc0[i], sqm0);
            k1[i] = fmaf(-2.0f, acc1[i], sqm1);
        }
        *reinterpret_cast<f32x4*>(kt + col16 * 20 + g * 4) = k0;
        *reinterpret_cast<f32x4*>(kt + (16 + col16) * 20 + g * 4) = k1;
        asm volatile("" ::: "memory");   // order LDS writes before same-wave reads

        // select: lane scans its 8 m-values for its row
        #pragma unroll
        for (int j = 0; j < 8; ++j) {
            int ml = mseg * 8 + j;
            float dist = kt[ml * 20 + srow] + sqn_r;
            int m = m0 + ml;
            unsigned u = __float_as_uint(dist);
            u = (u & 0x80000000u) ? ~u : (u | 0x80000000u);
            unsigned long long key = ((unsigned long long)u << 32) | (unsigned)m;
            if (key < cand[KNN - 1]) {
                cand[KNN - 1] = key;
                #pragma unroll
                for (int q = KNN - 1; q > 0; --q) {
                    unsigned long long lo2 = cand[q - 1], hi2 = cand[q];
                    if (hi2 < lo2) { cand[q - 1] = hi2; cand[q] = lo2; }
                }
            }
        }
    }

    // merge 4 partial lists per row (lanes 4*srow..+3), write sorted 9
    {
        int n = n0 + w * 16 + srow;
        size_t rowg = (size_t)b * N_PIX + n;
        for (int r = 0; r < KNN; ++r) {
            unsigned long long my = cand[0];
            unsigned long long gm = my;
            unsigned long long o1 = __shfl_xor(gm, 1); if (o1 < gm) gm = o1;
            unsigned long long o2 = __shfl_xor(gm, 2); if (o2 < gm) gm = o2;
            if (gm == my) {
                #pragma unroll
                for (int q = 0; q < KNN - 1; ++q) cand[q] = cand[q + 1];
                cand[KNN - 1] = ~0ull;
            }
            if (mseg == 0)
                pl[(rowg * 7 + mc) * KNN + r] = gm;
        }
    }
}

// ---------------- K3b: merge 7 sorted partial lists -> final idx (4 lanes/row) ----------------
__global__ __launch_bounds__(256) void k3b_merge(
    const unsigned long long* __restrict__ pl, int* __restrict__ idxout)
{
    int t = threadIdx.x;
    int r = blockIdx.x * 64 + (t >> 2);   // 196 blocks x 64 rows
    int s = t & 3;
    const unsigned long long* base = pl + (size_t)r * 63;
    unsigned long long cand[KNN];
    #pragma unroll
    for (int q = 0; q < KNN; ++q) cand[q] = ~0ull;
    for (int c = s; c < 7; c += 4) {
        const unsigned long long* ch = base + c * 9;
        #pragma unroll
        for (int q2 = 0; q2 < 9; ++q2) {
            unsigned long long k = ch[q2];
            if (k >= cand[KNN - 1]) break;    // chunk sorted ascending
            cand[KNN - 1] = k;
            #pragma unroll
            for (int q = KNN - 1; q > 0; --q) {
                unsigned long long lo = cand[q - 1], hi = cand[q];
                if (hi < lo) { cand[q - 1] = hi; cand[q] = lo; }
            }
        }
    }
    for (int rr = 0; rr < KNN; ++rr) {
        unsigned long long my = cand[0];
        unsigned long long gm = my;
        unsigned long long o1 = __shfl_xor(gm, 1); if (o1 < gm) gm = o1;
        unsigned long long o2 = __shfl_xor(gm, 2); if (o2 < gm) gm = o2;
        if (gm == my) {
            #pragma unroll
            for (int q = 0; q < KNN - 1; ++q) cand[q] = cand[q + 1];
            cand[KNN - 1] = ~0ull;
        }
        if (s == 0)
            idxout[(size_t)r * KNN + rr] = (int)(gm & 0xffffffffu);
    }
}

// ---------------- K2: P,Q = h @ Wc^T (+bias) -> bf16, MFMA, no LDS ----------------
__global__ __launch_bounds__(256, 2) void k2_pq(
    const u16* __restrict__ h2, const u16* __restrict__ wc2,
    const float* __restrict__ gcnb, u16* __restrict__ Pbf, u16* __restrict__ Qbf)
{
    int r0 = blockIdx.x * 64;
    int o0 = blockIdx.y * 32;
    int t = threadIdx.x, lane = t & 63, w = t >> 6;
    int col16 = lane & 15, g = lane >> 4;

    s16x8 a_hi[6], a_lo[6];
    {
        const u16* ar = h2 + (size_t)(r0 + w * 16 + col16) * 384;
        #pragma unroll
        for (int ko = 0; ko < 6; ++ko) {
            a_hi[ko] = *reinterpret_cast<const s16x8*>(ar + ko * 32 + g * 8);
            a_lo[ko] = *reinterpret_cast<const s16x8*>(ar + 192 + ko * 32 + g * 8);
        }
    }
    const u16* br = wc2 + (size_t)(o0 + col16) * 384 + g * 8;
    f32x4 acc0 = {0.f, 0.f, 0.f, 0.f};
    f32x4 acc1 = {0.f, 0.f, 0.f, 0.f};
    #pragma unroll
    for (int ko = 0; ko < 6; ++ko) {
        s16x8 b0h = *reinterpret_cast<const s16x8*>(br + ko * 32);
        s16x8 b0l = *reinterpret_cast<const s16x8*>(br + 192 + ko * 32);
        s16x8 b1h = *reinterpret_cast<const s16x8*>(br + 16 * 384 + ko * 32);
        s16x8 b1l = *reinterpret_cast<const s16x8*>(br + 16 * 384 + 192 + ko * 32);
        acc0 = __builtin_amdgcn_mfma_f32_16x16x32_bf16(a_hi[ko], b0h, acc0, 0, 0, 0);
        acc0 = __builtin_amdgcn_mfma_f32_16x16x32_bf16(a_hi[ko], b0l, acc0, 0, 0, 0);
        acc0 = __builtin_amdgcn_mfma_f32_16x16x32_bf16(a_lo[ko], b0h, acc0, 0, 0, 0);
        acc1 = __builtin_amdgcn_mfma_f32_16x16x32_bf16(a_hi[ko], b1h, acc1, 0, 0, 0);
        acc1 = __builtin_amdgcn_mfma_f32_16x16x32_bf16(a_hi[ko], b1l, acc1, 0, 0, 0);
        acc1 = __builtin_amdgcn_mfma_f32_16x16x32_bf16(a_lo[ko], b1h, acc1, 0, 0, 0);
    }
    bool isP = (o0 < HID_DIM);
    #pragma unroll
    for (int oq = 0; oq < 2; ++oq) {
        int o = o0 + oq * 16 + col16;
        float bias = isP ? gcnb[o] : 0.0f;
        #pragma unroll
        for (int i = 0; i < 4; ++i) {
            size_t r = (size_t)(r0 + w * 16 + g * 4 + i);
            float v = (oq ? acc1[i] : acc0[i]) + bias;
            u16 bv = f2bf_rn(v);
            if (isP) Pbf[r * 384 + o] = bv;
            else     Qbf[r * 384 + (o - HID_DIM)] = bv;
        }
    }
}

// ---------------- K4: g2 = split(gelu(bn_g(P + max_k Q[idx[k]]))) ----------------
__global__ __launch_bounds__(384) void k4_agg(
    const u16* __restrict__ Pbf, const u16* __restrict__ Qbf,
    const int* __restrict__ idx, const float* __restrict__ cst,
    u16* __restrict__ g2)
{
    int blk = blockIdx.x;
    int b = blk / N_PIX;
    size_t row = (size_t)blk;
    const int* id = idx + row * KNN;
    int o = threadIdx.x;
    const u16* Qb = Qbf + (size_t)b * N_PIX * 384;
    float v = -INFINITY;
    #pragma unroll
    for (int k = 0; k < KNN; ++k)
        v = fmaxf(v, bf2f(Qb[(size_t)id[k] * 384 + o]));
    float p = bf2f(Pbf[row * 384 + o]);
    float y = (p + v) * cst[384 + o] + cst[768 + o];
    float ge = 0.5f * y * (1.0f + erff(y * 0.70710678118654752f));
    u16 hi, lo; split2(ge, hi, lo);
    g2[row * 768 + o] = hi;
    g2[row * 768 + 384 + o] = lo;
}

// ---------------- K5: out = bn2(g @ fc2_w^T + fc2_b) + x, MFMA, no LDS ----------------
__global__ __launch_bounds__(256, 2) void k5_fc2_bn2(
    const u16* __restrict__ g2, const u16* __restrict__ w5,
    const float* __restrict__ fc2b, const float* __restrict__ cst,
    const float* __restrict__ x, float* __restrict__ out)
{
    int bx = blockIdx.x;
    int c0 = blockIdx.y * 32;
    int b  = bx / 49;
    int n0 = (bx % 49) * 64;
    int r0 = bx * 64;
    int t = threadIdx.x, lane = t & 63, w = t >> 6;
    int col16 = lane & 15, g = lane >> 4;

    const u16* ar = g2 + (size_t)(r0 + w * 16 + col16) * 768;
    const u16* br = w5 + (size_t)(c0 + col16) * 768 + g * 8;
    f32x4 acc0 = {0.f, 0.f, 0.f, 0.f};
    f32x4 acc1 = {0.f, 0.f, 0.f, 0.f};
    #pragma unroll
    for (int kh = 0; kh < 2; ++kh) {
        s16x8 a_hi[6], a_lo[6];
        #pragma unroll
        for (int ko = 0; ko < 6; ++ko) {
            a_hi[ko] = *reinterpret_cast<const s16x8*>(ar + (kh * 6 + ko) * 32 + g * 8);
            a_lo[ko] = *reinterpret_cast<const s16x8*>(ar + 384 + (kh * 6 + ko) * 32 + g * 8);
        }
        #pragma unroll
        for (int ko = 0; ko < 6; ++ko) {
            int kk = (kh * 6 + ko) * 32;
            s16x8 b0h = *reinterpret_cast<const s16x8*>(br + kk);
            s16x8 b0l = *reinterpret_cast<const s16x8*>(br + 384 + kk);
            s16x8 b1h = *reinterpret_cast<const s16x8*>(br + 16 * 768 + kk);
            s16x8 b1l = *reinterpret_cast<const s16x8*>(br + 16 * 768 + 384 + kk);
            acc0 = __builtin_amdgcn_mfma_f32_16x16x32_bf16(a_hi[ko], b0h, acc0, 0, 0, 0);
            acc0 = __builtin_amdgcn_mfma_f32_16x16x32_bf16(a_hi[ko], b0l, acc0, 0, 0, 0);
            acc0 = __builtin_amdgcn_mfma_f32_16x16x32_bf16(a_lo[ko], b0h, acc0, 0, 0, 0);
            acc1 = __builtin_amdgcn_mfma_f32_16x16x32_bf16(a_hi[ko], b1h, acc1, 0, 0, 0);
            acc1 = __builtin_amdgcn_mfma_f32_16x16x32_bf16(a_hi[ko], b1l, acc1, 0, 0, 0);
            acc1 = __builtin_amdgcn_mfma_f32_16x16x32_bf16(a_lo[ko], b1h, acc1, 0, 0, 0);
        }
    }
    #pragma unroll
    for (int oq = 0; oq < 2; ++oq) {
        int c = c0 + oq * 16 + col16;
        float s2 = cst[1152 + c], sh2 = cst[1344 + c], bz = fc2b[c];
        #pragma unroll
        for (int i = 0; i < 4; ++i) {
            int n = n0 + w * 16 + g * 4 + i;
            size_t a = (size_t)b * C_DIM * N_PIX + (size_t)c * N_PIX + n;
            float v = (oq ? acc1[i] : acc0[i]) + bz;
            out[a] = v * s2 + sh2 + x[a];
        }
    }
}

extern "C" void kernel_launch(void* const* d_in, const int* in_sizes, int n_in,
                              void* d_out, int out_size, void* d_ws, size_t ws_size,
                              hipStream_t stream)
{
    const float* x      = (const float*)d_in[0];
    const float* fc1_w  = (const float*)d_in[1];
    const float* fc1_b  = (const float*)d_in[2];
    const float* bn1_g  = (const float*)d_in[3];
    const float* bn1_b  = (const float*)d_in[4];
    const float* bn1_m  = (const float*)d_in[5];
    const float* bn1_v  = (const float*)d_in[6];
    const float* gcn_w  = (const float*)d_in[7];
    const float* gcn_b  = (const float*)d_in[8];
    const float* bng_g  = (const float*)d_in[9];
    const float* bng_b  = (const float*)d_in[10];
    const float* bng_m  = (const float*)d_in[11];
    const float* bng_v  = (const float*)d_in[12];
    const float* fc2_w  = (const float*)d_in[13];
    const float* fc2_b  = (const float*)d_in[14];
    const float* bn2_g  = (const float*)d_in[15];
    const float* bn2_b  = (const float*)d_in[16];
    const float* bn2_m  = (const float*)d_in[17];
    const float* bn2_v  = (const float*)d_in[18];
    float* out = (float*)d_out;

    float* ws  = (float*)d_ws;
    float* sqp = ws + OFF_SQP;
    float* sq  = ws + OFF_SQ;
    u16*   h2  = (u16*)(ws + OFF_H2);
    u16*   g2  = (u16*)(ws + OFF_G2);
    u16*   Pbf = (u16*)(ws + OFF_PBF);
    u16*   Qbf = (u16*)(ws + OFF_QBF);
    u16*   wc2 = (u16*)(ws + OFF_WC2);
    u16*   w5  = (u16*)(ws + OFF_W5);
    float* cst = ws + OFF_CST;
    int*   idx = (int*)(ws + OFF_IDX);
    unsigned long long* pl = (unsigned long long*)(ws + OFF_PL);

    k_prep<<<867, 256, 0, stream>>>(gcn_w, fc2_w,
                                    bn1_g, bn1_b, bn1_m, bn1_v,
                                    bng_g, bng_b, bng_m, bng_v,
                                    bn2_g, bn2_b, bn2_m, bn2_v, wc2, w5, cst);
    k1_fc1_bn1<<<dim3(196, 3), 256, 0, stream>>>(x, fc1_w, fc1_b, cst, h2, sqp);
    k_sqf<<<49, 256, 0, stream>>>(sqp, sq);
    k3_knn<<<1372, 256, 0, stream>>>(h2, sq, pl);
    k3b_merge<<<196, 256, 0, stream>>>(pl, idx);
    k2_pq<<<dim3(196, 24), 256, 0, stream>>>(h2, wc2, gcn_b, Pbf, Qbf);
    k4_agg<<<12544, 384, 0, stream>>>(Pbf, Qbf, idx, cst, g2);
    k5_fc2_bn2<<<dim3(196, 6), 256, 0, stream>>>(g2, w5, fc2_b, cst, x, out);
}